// Round 5
// baseline (27742.010 us; speedup 1.0000x reference)
//
#include <hip/hip_runtime.h>
#include <hip/hip_bf16.h>
#include <math.h>

// LSTM (N=64, T=1024, D=H=512) via bf16 MFMA.
// prep_wt: Wt[col][k] bf16 (2048 x 1024) in ws = [Wx;Wh] transposed.  (4 MB)
// lstm_step: one launch per t. 64 blocks x 512 thr (8 waves).
//   Block tile: all 64 batch rows x 32 cols (4 gates x 8 j), j0 = blk*8.
//   Wave (rowg = w&3, colg = w>>2): one 16x16 C tile, K=1024 -> 32 MFMA.
//   A-frag: fp32 x / h_prev loaded as 2x float4, converted in-lane to bf16.
//   B-frag: 16B load from Wt.
// c_state: fp32 in ws after Wt (128 KB). h_prev read from out[:, t-1, :].

#define TT 1024
#define HH 512
#define FH 2048
#define KK 1024

typedef __attribute__((ext_vector_type(8))) short bf16x8;
typedef __attribute__((ext_vector_type(4))) float f32x4;

__device__ __forceinline__ unsigned short f2bf(float f) {
    return __builtin_bit_cast(unsigned short, __float2bfloat16(f));
}

__global__ __launch_bounds__(256)
void prep_wt(const float* __restrict__ Wx, const float* __restrict__ Wh,
             unsigned short* __restrict__ Wt)
{
    __shared__ float tile[64][65];
    const int c0  = blockIdx.x * 64;   // col tile
    const int k0  = blockIdx.y * 64;   // k tile
    const int tid = threadIdx.x;

    #pragma unroll
    for (int it = 0; it < 16; ++it) {
        int idx = it * 256 + tid;
        int kk = idx >> 6, cc = idx & 63;
        int k = k0 + kk;
        float w = (k < 512) ? Wx[(size_t)k * FH + c0 + cc]
                            : Wh[(size_t)(k - 512) * FH + c0 + cc];
        tile[kk][cc] = w;
    }
    __syncthreads();

    #pragma unroll
    for (int it = 0; it < 8; ++it) {
        int idx = it * 256 + tid;
        int cc = idx >> 5, kp = idx & 31;
        unsigned int lo = f2bf(tile[kp * 2][cc]);
        unsigned int hi = f2bf(tile[kp * 2 + 1][cc]);
        *(unsigned int*)(Wt + (size_t)(c0 + cc) * KK + k0 + kp * 2) =
            lo | (hi << 16);
    }
}

__global__ __launch_bounds__(512)
void lstm_step(const float* __restrict__ x,
               const float* __restrict__ h0,
               const unsigned short* __restrict__ Wt,
               const float* __restrict__ b,
               float* __restrict__ out,
               float* __restrict__ c_state,
               int t)
{
    __shared__ float As[64][33];

    const int tid  = threadIdx.x;
    const int wv   = tid >> 6;
    const int lane = tid & 63;
    const int rowg = wv & 3;          // M tile (batch rows 16*rowg..)
    const int colg = wv >> 2;         // 0..1 (cols 16*colg..)
    const int j0   = blockIdx.x * 8;

    const int l15  = lane & 15;
    const int ksub = (lane >> 4) * 8;

    const int lc   = colg * 16 + l15;      // local col 0..31
    const int gate = lc >> 3;
    const int jj   = lc & 7;
    const int gcol = gate * HH + j0 + jj;  // global col in [0,2048)

    const int m = rowg * 16 + l15;         // batch row 0..63

    const unsigned short* wt = Wt + (size_t)gcol * KK + ksub;
    const float* xr = x + ((size_t)m * TT + t) * 512 + ksub;
    const float* hr = (t == 0) ? (h0 + (size_t)m * HH + ksub)
                               : (out + ((size_t)m * TT + (t - 1)) * HH + ksub);

    f32x4 acc = {0.f, 0.f, 0.f, 0.f};

    #pragma unroll
    for (int ks = 0; ks < 16; ++ks) {          // x part: k = ks*32 + ksub + e
        float4 u = *(const float4*)(xr + ks * 32);
        float4 v = *(const float4*)(xr + ks * 32 + 4);
        bf16x8 a;
        a[0] = (short)f2bf(u.x); a[1] = (short)f2bf(u.y);
        a[2] = (short)f2bf(u.z); a[3] = (short)f2bf(u.w);
        a[4] = (short)f2bf(v.x); a[5] = (short)f2bf(v.y);
        a[6] = (short)f2bf(v.z); a[7] = (short)f2bf(v.w);
        bf16x8 bb = *(const bf16x8*)(wt + ks * 32);
        acc = __builtin_amdgcn_mfma_f32_16x16x32_bf16(a, bb, acc, 0, 0, 0);
    }
    #pragma unroll
    for (int ks = 0; ks < 16; ++ks) {          // h part: k = 512 + ks*32 + ksub + e
        float4 u = *(const float4*)(hr + ks * 32);
        float4 v = *(const float4*)(hr + ks * 32 + 4);
        bf16x8 a;
        a[0] = (short)f2bf(u.x); a[1] = (short)f2bf(u.y);
        a[2] = (short)f2bf(u.z); a[3] = (short)f2bf(u.w);
        a[4] = (short)f2bf(v.x); a[5] = (short)f2bf(v.y);
        a[6] = (short)f2bf(v.z); a[7] = (short)f2bf(v.w);
        bf16x8 bb = *(const bf16x8*)(wt + 512 + ks * 32);
        acc = __builtin_amdgcn_mfma_f32_16x16x32_bf16(a, bb, acc, 0, 0, 0);
    }

    // C frag: col = lane&15 (+colbase), row = (lane>>4)*4 + r (+rowbase)
    #pragma unroll
    for (int r = 0; r < 4; ++r)
        As[rowg * 16 + (lane >> 4) * 4 + r][lc] = acc[r];

    __syncthreads();

    // gate phase: 512 cells = 64 rows x 8 j
    {
        int n = tid >> 3;
        int q = tid & 7;
        float Ai = As[n][q]      + b[j0 + q];
        float Af = As[n][8 + q]  + b[HH + j0 + q];
        float Ao = As[n][16 + q] + b[2 * HH + j0 + q];
        float Ag = As[n][24 + q] + b[3 * HH + j0 + q];

        float c_old = (t == 0) ? 0.f : c_state[(size_t)n * HH + j0 + q];

        float ig = 1.f / (1.f + __expf(-Ai));
        float fg = 1.f / (1.f + __expf(-Af));
        float og = 1.f / (1.f + __expf(-Ao));
        float gg = tanhf(Ag);

        float cn = fg * c_old + ig * gg;
        float hn = og * tanhf(cn);

        c_state[(size_t)n * HH + j0 + q] = cn;
        out[((size_t)n * TT + t) * HH + j0 + q] = hn;
    }
}

extern "C" void kernel_launch(void* const* d_in, const int* in_sizes, int n_in,
                              void* d_out, int out_size, void* d_ws, size_t ws_size,
                              hipStream_t stream)
{
    const float* x  = (const float*)d_in[0];
    const float* h0 = (const float*)d_in[1];
    const float* Wx = (const float*)d_in[2];
    const float* Wh = (const float*)d_in[3];
    const float* b  = (const float*)d_in[4];
    float* out = (float*)d_out;

    unsigned short* Wt = (unsigned short*)d_ws;                    // 4 MB
    float* c_state = (float*)((char*)d_ws + (size_t)FH * KK * 2);  // 128 KB

    prep_wt<<<dim3(32, 16), 256, 0, stream>>>(Wx, Wh, Wt);
    for (int t = 0; t < TT; ++t) {
        lstm_step<<<64, 512, 0, stream>>>(x, h0, Wt, b, out, c_state, t);
    }
}

// Round 6
// 27694.879 us; speedup vs baseline: 1.0017x; 1.0017x over previous
//
#include <hip/hip_runtime.h>
#include <hip/hip_bf16.h>
#include <math.h>

// LSTM (N=64, T=1024, D=H=512) via bf16 MFMA.
// prep_wt: Wt[col][k] bf16 (2048 x 1024) in ws = [Wx;Wh] transposed.  (4 MB)
// lstm_step: one launch per t. 64 blocks x 512 thr (8 waves).
//   Block tile: all 64 batch rows x 32 cols (4 gates x 8 j), j0 = blk*8.
//   Wave (rowg = w&3, colg = w>>2): one 16x16 C tile, K=1024 -> 32 MFMA.
//   A-frag: fp32 x / h_prev loaded as 2x float4, converted in-lane to bf16.
//   B-frag: 16B load from Wt.
// c_state: fp32 in ws after Wt (128 KB). h_prev read from out[:, t-1, :].

#define TT 1024
#define HH 512
#define FH 2048
#define KK 1024

typedef __attribute__((ext_vector_type(8))) short bf16x8;
typedef __attribute__((ext_vector_type(4))) float f32x4;

__device__ __forceinline__ unsigned short f2bf(float f) {
    return __builtin_bit_cast(unsigned short, __float2bfloat16(f));
}

__global__ __launch_bounds__(256)
void prep_wt(const float* __restrict__ Wx, const float* __restrict__ Wh,
             unsigned short* __restrict__ Wt)
{
    __shared__ float tile[64][65];
    const int c0  = blockIdx.x * 64;   // col tile
    const int k0  = blockIdx.y * 64;   // k tile
    const int tid = threadIdx.x;

    #pragma unroll
    for (int it = 0; it < 16; ++it) {
        int idx = it * 256 + tid;
        int kk = idx >> 6, cc = idx & 63;
        int k = k0 + kk;
        float w = (k < 512) ? Wx[(size_t)k * FH + c0 + cc]
                            : Wh[(size_t)(k - 512) * FH + c0 + cc];
        tile[kk][cc] = w;
    }
    __syncthreads();

    #pragma unroll
    for (int it = 0; it < 8; ++it) {
        int idx = it * 256 + tid;
        int cc = idx >> 5, kp = idx & 31;
        unsigned int lo = f2bf(tile[kp * 2][cc]);
        unsigned int hi = f2bf(tile[kp * 2 + 1][cc]);
        *(unsigned int*)(Wt + (size_t)(c0 + cc) * KK + k0 + kp * 2) =
            lo | (hi << 16);
    }
}

__global__ __launch_bounds__(512)
void lstm_step(const float* __restrict__ x,
               const float* __restrict__ h0,
               const unsigned short* __restrict__ Wt,
               const float* __restrict__ b,
               float* __restrict__ out,
               float* __restrict__ c_state,
               int t)
{
    __shared__ float As[64][33];

    const int tid  = threadIdx.x;
    const int wv   = tid >> 6;
    const int lane = tid & 63;
    const int rowg = wv & 3;          // M tile (batch rows 16*rowg..)
    const int colg = wv >> 2;         // 0..1 (cols 16*colg..)
    const int j0   = blockIdx.x * 8;

    const int l15  = lane & 15;
    const int ksub = (lane >> 4) * 8;

    const int lc   = colg * 16 + l15;      // local col 0..31
    const int gate = lc >> 3;
    const int jj   = lc & 7;
    const int gcol = gate * HH + j0 + jj;  // global col in [0,2048)

    const int m = rowg * 16 + l15;         // batch row 0..63

    const unsigned short* wt = Wt + (size_t)gcol * KK + ksub;
    const float* xr = x + ((size_t)m * TT + t) * 512 + ksub;
    const float* hr = (t == 0) ? (h0 + (size_t)m * HH + ksub)
                               : (out + ((size_t)m * TT + (t - 1)) * HH + ksub);

    f32x4 acc = {0.f, 0.f, 0.f, 0.f};

    #pragma unroll
    for (int ks = 0; ks < 16; ++ks) {          // x part: k = ks*32 + ksub + e
        float4 u = *(const float4*)(xr + ks * 32);
        float4 v = *(const float4*)(xr + ks * 32 + 4);
        bf16x8 a;
        a[0] = (short)f2bf(u.x); a[1] = (short)f2bf(u.y);
        a[2] = (short)f2bf(u.z); a[3] = (short)f2bf(u.w);
        a[4] = (short)f2bf(v.x); a[5] = (short)f2bf(v.y);
        a[6] = (short)f2bf(v.z); a[7] = (short)f2bf(v.w);
        bf16x8 bb = *(const bf16x8*)(wt + ks * 32);
        acc = __builtin_amdgcn_mfma_f32_16x16x32_bf16(a, bb, acc, 0, 0, 0);
    }
    #pragma unroll
    for (int ks = 0; ks < 16; ++ks) {          // h part: k = 512 + ks*32 + ksub + e
        float4 u = *(const float4*)(hr + ks * 32);
        float4 v = *(const float4*)(hr + ks * 32 + 4);
        bf16x8 a;
        a[0] = (short)f2bf(u.x); a[1] = (short)f2bf(u.y);
        a[2] = (short)f2bf(u.z); a[3] = (short)f2bf(u.w);
        a[4] = (short)f2bf(v.x); a[5] = (short)f2bf(v.y);
        a[6] = (short)f2bf(v.z); a[7] = (short)f2bf(v.w);
        bf16x8 bb = *(const bf16x8*)(wt + 512 + ks * 32);
        acc = __builtin_amdgcn_mfma_f32_16x16x32_bf16(a, bb, acc, 0, 0, 0);
    }

    // C frag: col = lane&15 (+colbase), row = (lane>>4)*4 + r (+rowbase)
    #pragma unroll
    for (int r = 0; r < 4; ++r)
        As[rowg * 16 + (lane >> 4) * 4 + r][lc] = acc[r];

    __syncthreads();

    // gate phase: 512 cells = 64 rows x 8 j
    {
        int n = tid >> 3;
        int q = tid & 7;
        float Ai = As[n][q]      + b[j0 + q];
        float Af = As[n][8 + q]  + b[HH + j0 + q];
        float Ao = As[n][16 + q] + b[2 * HH + j0 + q];
        float Ag = As[n][24 + q] + b[3 * HH + j0 + q];

        float c_old = (t == 0) ? 0.f : c_state[(size_t)n * HH + j0 + q];

        float ig = 1.f / (1.f + __expf(-Ai));
        float fg = 1.f / (1.f + __expf(-Af));
        float og = 1.f / (1.f + __expf(-Ao));
        float gg = tanhf(Ag);

        float cn = fg * c_old + ig * gg;
        float hn = og * tanhf(cn);

        c_state[(size_t)n * HH + j0 + q] = cn;
        out[((size_t)n * TT + t) * HH + j0 + q] = hn;
    }
}

extern "C" void kernel_launch(void* const* d_in, const int* in_sizes, int n_in,
                              void* d_out, int out_size, void* d_ws, size_t ws_size,
                              hipStream_t stream)
{
    const float* x  = (const float*)d_in[0];
    const float* h0 = (const float*)d_in[1];
    const float* Wx = (const float*)d_in[2];
    const float* Wh = (const float*)d_in[3];
    const float* b  = (const float*)d_in[4];
    float* out = (float*)d_out;

    unsigned short* Wt = (unsigned short*)d_ws;                    // 4 MB
    float* c_state = (float*)((char*)d_ws + (size_t)FH * KK * 2);  // 128 KB

    prep_wt<<<dim3(32, 16), 256, 0, stream>>>(Wx, Wh, Wt);
    for (int t = 0; t < TT; ++t) {
        lstm_step<<<64, 512, 0, stream>>>(x, h0, Wt, b, out, c_state, t);
    }
}

// Round 7
// 11842.811 us; speedup vs baseline: 2.3425x; 2.3385x over previous
//
#include <hip/hip_runtime.h>
#include <hip/hip_bf16.h>
#include <math.h>

// LSTM (N=64, T=1024, D=H=512), persistent-kernel bf16-MFMA version.
//
// ws layout:
//   Wt  bf16 [2048][1024]  @ 0        (4 MB)   [Wx;Wh]^T, col-major-K
//   hb  bf16 [2][64][512]  @ 4MB      (128 KB) h_t panels (double buffered)
//   xb  bf16 [2][64][512]  @ 4MB+128K (128 KB) x_t panels (double buffered)
//   ctr u32  [1024][16]    @ 4MB+256K (64 KB)  per-step barrier counters
//
// Persistent kernel: 64 blocks x 512 thr, t-loop inside. Block = rows
// mg*32..+32 x 16 j-cols (x4 gates). Cross-block traffic (hb/xb/ctr) uses
// sc0 sc1 (L3-coherent, never cached in L1/L2) so Wt stays L2-resident.
// c-state lives in registers (fixed owner thread). out written fp32 (plain).

#define TT 1024
#define HH 512
#define FH 2048
#define KK 1024
#define NN 64
#define NBLK 64

typedef __attribute__((ext_vector_type(8))) short bf16x8;
typedef __attribute__((ext_vector_type(4))) float f32x4;
typedef __attribute__((ext_vector_type(4))) int int4v;

__device__ __forceinline__ unsigned short f2bf(float f) {
    return __builtin_bit_cast(unsigned short, __float2bfloat16(f));
}

// ---------------- prep: Wt[col][k] = [Wx;Wh]^T bf16 ----------------
__global__ __launch_bounds__(256)
void prep_wt(const float* __restrict__ Wx, const float* __restrict__ Wh,
             unsigned short* __restrict__ Wt)
{
    __shared__ float tile[64][65];
    const int c0  = blockIdx.x * 64;
    const int k0  = blockIdx.y * 64;
    const int tid = threadIdx.x;

    #pragma unroll
    for (int it = 0; it < 16; ++it) {
        int idx = it * 256 + tid;
        int kk = idx >> 6, cc = idx & 63;
        int k = k0 + kk;
        float w = (k < 512) ? Wx[(size_t)k * FH + c0 + cc]
                            : Wh[(size_t)(k - 512) * FH + c0 + cc];
        tile[kk][cc] = w;
    }
    __syncthreads();

    #pragma unroll
    for (int it = 0; it < 8; ++it) {
        int idx = it * 256 + tid;
        int cc = idx >> 5, kp = idx & 31;
        unsigned int lo = f2bf(tile[kp * 2][cc]);
        unsigned int hi = f2bf(tile[kp * 2 + 1][cc]);
        *(unsigned int*)(Wt + (size_t)(c0 + cc) * KK + k0 + kp * 2) =
            lo | (hi << 16);
    }
}

// ---------------- init: zero ctr, seed hb[0] / xb[0] ----------------
__global__ __launch_bounds__(256)
void lstm_init(const float* __restrict__ h0, const float* __restrict__ x,
               unsigned short* __restrict__ hb, unsigned short* __restrict__ xb,
               unsigned int* __restrict__ ctr)
{
    int id = blockIdx.x * 256 + threadIdx.x;
    if (id < 1024 * 16) {
        unsigned int* p = ctr + id;
        unsigned int z = 0u;
        asm volatile("global_store_dword %0, %1, off sc0 sc1" :: "v"(p), "v"(z) : "memory");
    }
    if (id < NN * HH) {
        unsigned int hv = (unsigned int)f2bf(h0[id]);
        unsigned short* hp = hb + id;
        asm volatile("global_store_short %0, %1, off sc0 sc1" :: "v"(hp), "v"(hv) : "memory");
        int n = id >> 9, d = id & 511;
        unsigned int xv = (unsigned int)f2bf(x[(size_t)n * TT * 512 + d]);
        unsigned short* xp = xb + id;
        asm volatile("global_store_short %0, %1, off sc0 sc1" :: "v"(xp), "v"(xv) : "memory");
    }
}

// ---------------- persistent recurrence ----------------
__global__ __launch_bounds__(512)
void lstm_persist(const float* __restrict__ x,
                  const unsigned short* __restrict__ Wt,
                  const float* __restrict__ b,
                  float* __restrict__ out,
                  unsigned short* __restrict__ hb,
                  unsigned short* __restrict__ xb,
                  unsigned int* __restrict__ ctr)
{
    __shared__ __align__(16) unsigned short Ap[32 * 1024]; // 64 KB swizzled A panel
    __shared__ float As[32][68];                            // A tile for gate phase

    const int tid  = threadIdx.x;
    const int wv   = tid >> 6;
    const int lane = tid & 63;
    const int l15  = lane & 15;
    const int kh   = lane >> 4;            // 0..3
    const int mg   = blockIdx.x >> 5;      // 0..1 (row half)
    const int jg   = blockIdx.x & 31;      // 0..31
    const int j0   = jg * 16;

    const int rg = wv & 1;                 // row group within block
    const int cg = wv >> 1;                // 0..3 col group
    const int lc   = cg * 16 + l15;        // local col 0..63
    const int gate = lc >> 4;
    const int jj   = lc & 15;
    const int gcol = gate * HH + j0 + jj;

    const unsigned short* wtp = Wt + (size_t)gcol * KK + kh * 8;

    // LDS A-frag addressing (ushort units), XOR swizzle (row&7)<<3 ushorts
    const int arow = rg * 16 + l15;
    const int rsw  = (arow & 7) << 3;
    const unsigned short* apr = Ap + arow * 1024;

    // gate-phase cell ownership (fixed for all t)
    const int lrow = tid >> 4;             // 0..31
    const int q    = tid & 15;
    const int grow = mg * 32 + lrow;       // global batch row
    const int gj   = j0 + q;               // global h col
    const float bi = b[gj], bfv = b[HH + gj], bo = b[2 * HH + gj], bg = b[3 * HH + gj];
    float c_reg = 0.f;
    float* outp = out + (size_t)grow * TT * HH + gj;
    unsigned short* hdst_base = hb + (size_t)grow * HH + gj;

    // stage-phase fixed coords: chunk id = i*512 + tid
    const int c16 = tid & 127;             // 16B chunk within row
    const int rb  = tid >> 7;              // 0..3 base row
    const int xrow = blockIdx.x;           // convert: this block converts x row blockIdx.x

    for (int t = 0; t < TT; ++t) {
        const int cur = t & 1;
        const int nxt = (t + 1) & 1;

        // ---- STAGE: A panel (rows mg*32..+32, k<512 = xb, k>=512 = hb) ----
        const unsigned short* xsrc = xb + (size_t)cur * NN * HH + (size_t)mg * 32 * HH;
        const unsigned short* hsrc = hb + (size_t)cur * NN * HH + (size_t)mg * 32 * HH;
        const unsigned short* srcbase = (c16 < 64)
            ? xsrc + (size_t)rb * 512 + c16 * 8
            : hsrc + (size_t)rb * 512 + (c16 - 64) * 8;

        int4v r[8];
        #pragma unroll
        for (int i = 0; i < 8; ++i) {
            asm volatile("global_load_dwordx4 %0, %1, off sc0 sc1"
                         : "=v"(r[i]) : "v"(srcbase + (size_t)i * 2048));
        }
        asm volatile("s_waitcnt vmcnt(0)" ::: "memory");
        #pragma unroll
        for (int i = 0; i < 8; ++i) {
            int row = i * 4 + rb;
            *(int4v*)(Ap + row * 1024 + ((c16 * 8) ^ ((row & 7) << 3))) = r[i];
        }
        __syncthreads();

        // ---- CONVERT x_{t+1} -> xb[nxt] (block converts its one row) ----
        if (t < TT - 1 && tid < 256) {
            float2 xv = *(const float2*)(x + ((size_t)xrow * TT + t + 1) * 512 + tid * 2);
            unsigned int pk = (unsigned int)f2bf(xv.x) | ((unsigned int)f2bf(xv.y) << 16);
            unsigned short* dst = xb + (size_t)nxt * NN * HH + (size_t)xrow * HH + tid * 2;
            asm volatile("global_store_dword %0, %1, off sc0 sc1" :: "v"(dst), "v"(pk) : "memory");
        }

        // ---- GEMM: wave tile 16x16, K=1024 -> 32 MFMA ----
        f32x4 acc = {0.f, 0.f, 0.f, 0.f};
        #pragma unroll 8
        for (int ks = 0; ks < 32; ++ks) {
            bf16x8 a  = *(const bf16x8*)(apr + ((ks * 32 + kh * 8) ^ rsw));
            bf16x8 bb = *(const bf16x8*)(wtp + ks * 32);
            acc = __builtin_amdgcn_mfma_f32_16x16x32_bf16(a, bb, acc, 0, 0, 0);
        }
        #pragma unroll
        for (int rr = 0; rr < 4; ++rr)
            As[rg * 16 + kh * 4 + rr][lc] = acc[rr];
        __syncthreads();

        // ---- GATES (every thread owns one cell) ----
        {
            float Ai = As[lrow][q]      + bi;
            float Af = As[lrow][16 + q] + bfv;
            float Ao = As[lrow][32 + q] + bo;
            float Ag = As[lrow][48 + q] + bg;
            float ig = 1.f / (1.f + __expf(-Ai));
            float fg = 1.f / (1.f + __expf(-Af));
            float og = 1.f / (1.f + __expf(-Ao));
            float gg = tanhf(Ag);
            c_reg = fg * c_reg + ig * gg;
            float hn = og * tanhf(c_reg);
            outp[(size_t)t * HH] = hn;
            unsigned int hv = (unsigned int)f2bf(hn);
            unsigned short* hdst = hdst_base + (size_t)nxt * NN * HH;
            asm volatile("global_store_short %0, %1, off sc0 sc1" :: "v"(hdst), "v"(hv) : "memory");
        }

        // ---- BARRIER (skip after last step) ----
        if (t < TT - 1) {
            asm volatile("s_waitcnt vmcnt(0)" ::: "memory");
            __syncthreads();
            if (tid == 0) {
                unsigned int* cp = ctr + (size_t)t * 16;
                unsigned int one = 1u;
                asm volatile("global_atomic_add %0, %1, off sc1" :: "v"(cp), "v"(one) : "memory");
                unsigned int v;
                do {
                    asm volatile("global_load_dword %0, %1, off sc0 sc1\n\t"
                                 "s_waitcnt vmcnt(0)"
                                 : "=v"(v) : "v"(cp) : "memory");
                } while (v < NBLK);
            }
            __syncthreads();
        }
    }
}

extern "C" void kernel_launch(void* const* d_in, const int* in_sizes, int n_in,
                              void* d_out, int out_size, void* d_ws, size_t ws_size,
                              hipStream_t stream)
{
    const float* x  = (const float*)d_in[0];
    const float* h0 = (const float*)d_in[1];
    const float* Wx = (const float*)d_in[2];
    const float* Wh = (const float*)d_in[3];
    const float* b  = (const float*)d_in[4];
    float* out = (float*)d_out;

    char* ws = (char*)d_ws;
    unsigned short* Wt  = (unsigned short*)ws;                         // 4 MB
    unsigned short* hb  = (unsigned short*)(ws + (size_t)4 * 1024 * 1024);          // 128 KB
    unsigned short* xb  = (unsigned short*)(ws + (size_t)4 * 1024 * 1024 + 131072); // 128 KB
    unsigned int*   ctr = (unsigned int*)(ws + (size_t)4 * 1024 * 1024 + 262144);   // 64 KB

    prep_wt<<<dim3(32, 16), 256, 0, stream>>>(Wx, Wh, Wt);
    lstm_init<<<128, 256, 0, stream>>>(h0, x, hb, xb, ctr);
    lstm_persist<<<NBLK, 512, 0, stream>>>(x, Wt, b, out, hb, xb, ctr);
}

// Round 8
// 4003.464 us; speedup vs baseline: 6.9295x; 2.9581x over previous
//
#include <hip/hip_runtime.h>
#include <hip/hip_bf16.h>
#include <math.h>

// LSTM (N=64, T=1024, D=H=512), persistent-kernel bf16-MFMA version, v2.
//
// ws layout:
//   Wt  bf16 [2048][1024]  @ 0        (4 MB)   [Wx;Wh]^T, col-major-K
//   hb  bf16 [2][64][512]  @ 4MB      (128 KB) h_t panels (double buffered)
//   xb  bf16 [2][64][512]  @ 4MB+128K (128 KB) x_t panels (double buffered)
//   flg u32  [64*16]       @ 4MB+256K (4 KB)   per-block monotonic flags
//
// v2 changes vs round 7:
//  - barrier: per-block flag + 64-lane poll (no atomic serialization)
//  - B-fragments hoisted to registers (loop-invariant across t): 128 VGPRs
//  - full-rank LDS swizzle m(row)=((row&15)<<3)|((row&3)<<7): conflict-free

#define TT 1024
#define HH 512
#define FH 2048
#define KK 1024
#define NN 64
#define NBLK 64

typedef __attribute__((ext_vector_type(8))) short bf16x8;
typedef __attribute__((ext_vector_type(4))) float f32x4;
typedef __attribute__((ext_vector_type(4))) int int4v;

__device__ __forceinline__ unsigned short f2bf(float f) {
    return __builtin_bit_cast(unsigned short, __float2bfloat16(f));
}

// ---------------- prep: Wt[col][k] = [Wx;Wh]^T bf16 ----------------
__global__ __launch_bounds__(256)
void prep_wt(const float* __restrict__ Wx, const float* __restrict__ Wh,
             unsigned short* __restrict__ Wt)
{
    __shared__ float tile[64][65];
    const int c0  = blockIdx.x * 64;
    const int k0  = blockIdx.y * 64;
    const int tid = threadIdx.x;

    #pragma unroll
    for (int it = 0; it < 16; ++it) {
        int idx = it * 256 + tid;
        int kk = idx >> 6, cc = idx & 63;
        int k = k0 + kk;
        float w = (k < 512) ? Wx[(size_t)k * FH + c0 + cc]
                            : Wh[(size_t)(k - 512) * FH + c0 + cc];
        tile[kk][cc] = w;
    }
    __syncthreads();

    #pragma unroll
    for (int it = 0; it < 8; ++it) {
        int idx = it * 256 + tid;
        int cc = idx >> 5, kp = idx & 31;
        unsigned int lo = f2bf(tile[kp * 2][cc]);
        unsigned int hi = f2bf(tile[kp * 2 + 1][cc]);
        *(unsigned int*)(Wt + (size_t)(c0 + cc) * KK + k0 + kp * 2) =
            lo | (hi << 16);
    }
}

// ---------------- init: zero flags, seed hb[0] / xb[0] ----------------
__global__ __launch_bounds__(256)
void lstm_init(const float* __restrict__ h0, const float* __restrict__ x,
               unsigned short* __restrict__ hb, unsigned short* __restrict__ xb,
               unsigned int* __restrict__ flg)
{
    int id = blockIdx.x * 256 + threadIdx.x;
    if (id < NBLK * 16) {
        unsigned int* p = flg + id;
        unsigned int z = 0u;
        asm volatile("global_store_dword %0, %1, off sc0 sc1" :: "v"(p), "v"(z) : "memory");
    }
    if (id < NN * HH) {
        unsigned int hv = (unsigned int)f2bf(h0[id]);
        unsigned short* hp = hb + id;
        asm volatile("global_store_short %0, %1, off sc0 sc1" :: "v"(hp), "v"(hv) : "memory");
        int n = id >> 9, d = id & 511;
        unsigned int xv = (unsigned int)f2bf(x[(size_t)n * TT * 512 + d]);
        unsigned short* xp = xb + id;
        asm volatile("global_store_short %0, %1, off sc0 sc1" :: "v"(xp), "v"(xv) : "memory");
    }
}

// ---------------- persistent recurrence ----------------
__global__ __launch_bounds__(512, 2)
void lstm_persist(const float* __restrict__ x,
                  const unsigned short* __restrict__ Wt,
                  const float* __restrict__ b,
                  float* __restrict__ out,
                  unsigned short* __restrict__ hb,
                  unsigned short* __restrict__ xb,
                  unsigned int* __restrict__ flg)
{
    __shared__ __align__(16) unsigned short Ap[32 * 1024]; // 64 KB swizzled A panel
    __shared__ float As[32][68];                            // A tile for gate phase

    const int tid  = threadIdx.x;
    const int wv   = tid >> 6;
    const int lane = tid & 63;
    const int l15  = lane & 15;
    const int kh   = lane >> 4;            // 0..3
    const int mg   = blockIdx.x >> 5;      // 0..1 (row half)
    const int jg   = blockIdx.x & 31;      // 0..31
    const int j0   = jg * 16;

    const int rg = wv & 1;                 // row group within block
    const int cg = wv >> 1;                // 0..3 col group
    const int lc   = cg * 16 + l15;        // local col 0..63
    const int gate = lc >> 4;
    const int jj   = lc & 15;
    const int gcol = gate * HH + j0 + jj;

    // ---- hoist B fragments (loop-invariant across t): 32 x bf16x8 ----
    const unsigned short* wtp = Wt + (size_t)gcol * KK + kh * 8;
    bf16x8 breg[32];
    #pragma unroll
    for (int ks = 0; ks < 32; ++ks)
        breg[ks] = *(const bf16x8*)(wtp + ks * 32);

    // LDS A-frag addressing (ushort units), full-rank XOR swizzle
    const int arow = rg * 16 + l15;
    const int rsw  = ((arow & 15) << 3) | ((arow & 3) << 7);
    const unsigned short* apr = Ap + arow * 1024;

    // gate-phase cell ownership (fixed for all t)
    const int lrow = tid >> 4;             // 0..31
    const int q    = tid & 15;
    const int grow = mg * 32 + lrow;       // global batch row
    const int gj   = j0 + q;               // global h col
    const float bi = b[gj], bfv = b[HH + gj], bo = b[2 * HH + gj], bg = b[3 * HH + gj];
    float c_reg = 0.f;
    float* outp = out + (size_t)grow * TT * HH + gj;
    unsigned short* hdst_base = hb + (size_t)grow * HH + gj;

    // stage-phase fixed coords: chunk id = i*512 + tid
    const int c16 = tid & 127;             // 16B chunk within row
    const int rb  = tid >> 7;              // 0..3 base row
    const int xrow = blockIdx.x;           // this block converts x row blockIdx.x

    for (int t = 0; t < TT; ++t) {
        const int cur = t & 1;
        const int nxt = (t + 1) & 1;

        // ---- STAGE: A panel (rows mg*32..+32, k<512 = xb, k>=512 = hb) ----
        const unsigned short* xsrc = xb + (size_t)cur * NN * HH + (size_t)mg * 32 * HH;
        const unsigned short* hsrc = hb + (size_t)cur * NN * HH + (size_t)mg * 32 * HH;
        const unsigned short* srcbase = (c16 < 64)
            ? xsrc + (size_t)rb * 512 + c16 * 8
            : hsrc + (size_t)rb * 512 + (c16 - 64) * 8;

        int4v r[8];
        #pragma unroll
        for (int i = 0; i < 8; ++i) {
            asm volatile("global_load_dwordx4 %0, %1, off sc0 sc1"
                         : "=v"(r[i]) : "v"(srcbase + (size_t)i * 2048));
        }
        asm volatile("s_waitcnt vmcnt(0)" ::: "memory");
        #pragma unroll
        for (int i = 0; i < 8; ++i) {
            int row = i * 4 + rb;
            int m   = ((row & 15) << 3) | ((row & 3) << 7);
            *(int4v*)(Ap + row * 1024 + ((c16 * 8) ^ m)) = r[i];
        }
        __syncthreads();

        // ---- CONVERT x_{t+1} -> xb[nxt] (block converts its one row) ----
        if (t < TT - 1 && tid < 256) {
            float2 xv = *(const float2*)(x + ((size_t)xrow * TT + t + 1) * 512 + tid * 2);
            unsigned int pk = (unsigned int)f2bf(xv.x) | ((unsigned int)f2bf(xv.y) << 16);
            unsigned short* dst = xb + (size_t)nxt * NN * HH + (size_t)xrow * HH + tid * 2;
            asm volatile("global_store_dword %0, %1, off sc0 sc1" :: "v"(dst), "v"(pk) : "memory");
        }

        // ---- GEMM: wave tile 16x16, K=1024 -> 32 MFMA, B from registers ----
        f32x4 acc = {0.f, 0.f, 0.f, 0.f};
        #pragma unroll
        for (int ks = 0; ks < 32; ++ks) {
            bf16x8 a = *(const bf16x8*)(apr + ((ks * 32 + kh * 8) ^ rsw));
            acc = __builtin_amdgcn_mfma_f32_16x16x32_bf16(a, breg[ks], acc, 0, 0, 0);
        }
        #pragma unroll
        for (int rr = 0; rr < 4; ++rr)
            As[rg * 16 + kh * 4 + rr][lc] = acc[rr];
        __syncthreads();

        // ---- GATES (every thread owns one cell) ----
        {
            float Ai = As[lrow][q]      + bi;
            float Af = As[lrow][16 + q] + bfv;
            float Ao = As[lrow][32 + q] + bo;
            float Ag = As[lrow][48 + q] + bg;
            float ig = 1.f / (1.f + __expf(-Ai));
            float fg = 1.f / (1.f + __expf(-Af));
            float og = 1.f / (1.f + __expf(-Ao));
            float gg = tanhf(Ag);
            c_reg = fg * c_reg + ig * gg;
            float hn = og * tanhf(c_reg);
            outp[(size_t)t * HH] = hn;
            unsigned int hv = (unsigned int)f2bf(hn);
            unsigned short* hdst = hdst_base + (size_t)nxt * NN * HH;
            asm volatile("global_store_short %0, %1, off sc0 sc1" :: "v"(hdst), "v"(hv) : "memory");
        }

        // ---- BARRIER: per-block flag + 64-lane poll (skip after last step) ----
        if (t < TT - 1) {
            asm volatile("s_waitcnt vmcnt(0)" ::: "memory");
            __syncthreads();
            if (wv == 0) {
                const unsigned int target = (unsigned int)(t + 1);
                if (lane == 0) {
                    unsigned int* fp = flg + (size_t)blockIdx.x * 16;
                    asm volatile("global_store_dword %0, %1, off sc0 sc1"
                                 :: "v"(fp), "v"(target) : "memory");
                }
                const unsigned int* pp = flg + (size_t)lane * 16;
                unsigned int v;
                do {
                    asm volatile("global_load_dword %0, %1, off sc0 sc1\n\t"
                                 "s_waitcnt vmcnt(0)"
                                 : "=v"(v) : "v"(pp) : "memory");
                } while (!__all(v >= target));
            }
            __syncthreads();
        }
    }
}

extern "C" void kernel_launch(void* const* d_in, const int* in_sizes, int n_in,
                              void* d_out, int out_size, void* d_ws, size_t ws_size,
                              hipStream_t stream)
{
    const float* x  = (const float*)d_in[0];
    const float* h0 = (const float*)d_in[1];
    const float* Wx = (const float*)d_in[2];
    const float* Wh = (const float*)d_in[3];
    const float* b  = (const float*)d_in[4];
    float* out = (float*)d_out;

    char* ws = (char*)d_ws;
    unsigned short* Wt  = (unsigned short*)ws;                                      // 4 MB
    unsigned short* hb  = (unsigned short*)(ws + (size_t)4 * 1024 * 1024);          // 128 KB
    unsigned short* xb  = (unsigned short*)(ws + (size_t)4 * 1024 * 1024 + 131072); // 128 KB
    unsigned int*   flg = (unsigned int*)(ws + (size_t)4 * 1024 * 1024 + 262144);   // 4 KB

    prep_wt<<<dim3(32, 16), 256, 0, stream>>>(Wx, Wh, Wt);
    lstm_init<<<128, 256, 0, stream>>>(h0, x, hb, xb, flg);
    lstm_persist<<<NBLK, 512, 0, stream>>>(x, Wt, b, out, hb, xb, flg);
}

// Round 9
// 3279.833 us; speedup vs baseline: 8.4584x; 1.2206x over previous
//
#include <hip/hip_runtime.h>
#include <hip/hip_bf16.h>
#include <math.h>

// LSTM (N=64, T=1024, D=H=512), persistent-kernel bf16-MFMA v3.
//
// ws layout:
//   Wt  bf16 [2048][1024]  @ 0        (4 MB)   [Wx;Wh]^T, col-major-K
//   hb  bf16 [2][64][512]  @ 4MB      (128 KB) h panels (double buffered)
//   flg u32  [256*16]      @ 4MB+128K (16 KB)  per-block monotonic flags
//
// 256 blocks = 4 row-groups (16 batch rows) x 64 j-groups (8 h-cols x 4 gates
// = 32 A-cols). 512 thr = 8 waves = 2 col-tiles x 4-way K-split (4+4 MFMA).
// x_{t+1} prefetched fp32->regs during step t (x read-only, plain loads).
// x-GEMM runs BEFORE the flag barrier; only h-half waits. c in registers.

#define TT 1024
#define HH 512
#define FH 2048
#define KK 1024
#define NN 64

typedef __attribute__((ext_vector_type(8))) short bf16x8;
typedef __attribute__((ext_vector_type(4))) float f32x4;
typedef __attribute__((ext_vector_type(4))) int int4v;

__device__ __forceinline__ unsigned short f2bf(float f) {
    return __builtin_bit_cast(unsigned short, __float2bfloat16(f));
}

// ---------------- prep: Wt[col][k] = [Wx;Wh]^T bf16 ----------------
__global__ __launch_bounds__(256)
void prep_wt(const float* __restrict__ Wx, const float* __restrict__ Wh,
             unsigned short* __restrict__ Wt)
{
    __shared__ float tile[64][65];
    const int c0  = blockIdx.x * 64;
    const int k0  = blockIdx.y * 64;
    const int tid = threadIdx.x;

    #pragma unroll
    for (int it = 0; it < 16; ++it) {
        int idx = it * 256 + tid;
        int kk = idx >> 6, cc = idx & 63;
        int k = k0 + kk;
        float w = (k < 512) ? Wx[(size_t)k * FH + c0 + cc]
                            : Wh[(size_t)(k - 512) * FH + c0 + cc];
        tile[kk][cc] = w;
    }
    __syncthreads();

    #pragma unroll
    for (int it = 0; it < 8; ++it) {
        int idx = it * 256 + tid;
        int cc = idx >> 5, kp = idx & 31;
        unsigned int lo = f2bf(tile[kp * 2][cc]);
        unsigned int hi = f2bf(tile[kp * 2 + 1][cc]);
        *(unsigned int*)(Wt + (size_t)(c0 + cc) * KK + k0 + kp * 2) =
            lo | (hi << 16);
    }
}

// ---------------- init: zero flags, seed hb[0] ----------------
__global__ __launch_bounds__(256)
void lstm_init(const float* __restrict__ h0,
               unsigned short* __restrict__ hb,
               unsigned int* __restrict__ flg)
{
    int id = blockIdx.x * 256 + threadIdx.x;
    if (id < 256 * 16) {
        unsigned int* p = flg + id;
        unsigned int z = 0u;
        asm volatile("global_store_dword %0, %1, off sc0 sc1" :: "v"(p), "v"(z) : "memory");
    }
    if (id < NN * HH) {
        unsigned int hv = (unsigned int)f2bf(h0[id]);
        unsigned short* hp = hb + id;
        asm volatile("global_store_short %0, %1, off sc0 sc1" :: "v"(hp), "v"(hv) : "memory");
    }
}

// ---------------- persistent recurrence ----------------
__global__ __launch_bounds__(512, 2)
void lstm_persist(const float* __restrict__ x,
                  const unsigned short* __restrict__ Wt,
                  const float* __restrict__ bias,
                  float* __restrict__ out,
                  unsigned short* __restrict__ hb,
                  unsigned int* __restrict__ flg)
{
    __shared__ __align__(16) unsigned short Ap[16 * 1024]; // 32 KB swizzled A panel
    __shared__ float part[8][16][16];                       // 8 KB partials
    __shared__ float As[16][33];                            // reduced A tile

    const int tid  = threadIdx.x;
    const int wv   = tid >> 6;
    const int lane = tid & 63;
    const int l15  = lane & 15;
    const int kh   = lane >> 4;            // 0..3

    const int rg = blockIdx.x >> 6;        // row-group 0..3 (rows rg*16..+16)
    const int jg = blockIdx.x & 63;        // j-group 0..63 (cols jg*8..+8)
    const int j0 = jg * 8;
    const int rowbase = rg * 16;

    const int ct = wv & 1;                 // col-tile 0..1
    const int kq = wv >> 1;                // K-quarter 0..3

    const int lc   = ct * 16 + l15;        // local A-col 0..31
    const int gate = lc >> 3;
    const int jj   = lc & 7;
    const int gcol = gate * HH + j0 + jj;

    // ---- hoist B fragments: 4 x-part + 4 h-part (32 VGPR) ----
    const unsigned short* wtp = Wt + (size_t)gcol * KK + kh * 8;
    bf16x8 bx[4], bh[4];
    #pragma unroll
    for (int ks = 0; ks < 4; ++ks) {
        bx[ks] = *(const bf16x8*)(wtp + kq * 128 + ks * 32);
        bh[ks] = *(const bf16x8*)(wtp + 512 + kq * 128 + ks * 32);
    }

    // A-frag read addressing (ushort units), swizzle (row&7)<<3
    const int arow = l15;                  // batch row within block
    const int rsw  = (arow & 7) << 3;
    const unsigned short* apr = Ap + arow * 1024;

    // staging coords: row = tid>>5 (0..15), scol = tid&31
    const int srow = tid >> 5;
    const int scol = tid & 31;
    const int rws  = (srow & 7) << 3;
    const float* xrow_ptr = x + (size_t)(rowbase + srow) * TT * 512 + scol * 16;

    // gate-phase ownership (tid < 128 active)
    const int grow_l = (tid < 128) ? (tid >> 3) : 0;
    const int q      = tid & 7;
    const int grow   = rowbase + grow_l;
    const int gj     = j0 + q;
    float bi = 0.f, bf_ = 0.f, bo = 0.f, bg = 0.f;
    if (tid < 128) {
        bi  = bias[gj];
        bf_ = bias[HH + gj];
        bo  = bias[2 * HH + gj];
        bg  = bias[3 * HH + gj];
    }
    float c_reg = 0.f;
    float* outp = out + (size_t)grow * TT * HH + gj;
    unsigned short* hdst0 = hb + (size_t)grow * HH + gj;

    unsigned int* myflag = flg + (size_t)blockIdx.x * 16;
    const unsigned int* pollp = flg + (size_t)(rg * 64 + lane) * 16;

    // ---- prologue: prefetch x for t=0 ----
    float4 xpf[4];
    #pragma unroll
    for (int i = 0; i < 4; ++i)
        xpf[i] = *(const float4*)(xrow_ptr + i * 4);

    for (int t = 0; t < TT; ++t) {
        const int cur = t & 1;
        const int nxt = cur ^ 1;

        // ---- write x-half of Ap from prefetched regs (16 bf16 / thread) ----
        {
            unsigned int pk[8];
            #pragma unroll
            for (int i = 0; i < 4; ++i) {
                pk[2 * i]     = (unsigned int)f2bf(xpf[i].x) | ((unsigned int)f2bf(xpf[i].y) << 16);
                pk[2 * i + 1] = (unsigned int)f2bf(xpf[i].z) | ((unsigned int)f2bf(xpf[i].w) << 16);
            }
            int k0u = scol * 16;
            *(int4v*)(Ap + srow * 1024 + (k0u ^ rws))       = *(int4v*)&pk[0];
            *(int4v*)(Ap + srow * 1024 + ((k0u + 8) ^ rws)) = *(int4v*)&pk[4];
        }
        __syncthreads();   // s1: x-half visible

        // ---- x-GEMM (no cross-block dependency): 4 MFMA ----
        f32x4 acc = {0.f, 0.f, 0.f, 0.f};
        #pragma unroll
        for (int ks = 0; ks < 4; ++ks) {
            bf16x8 a = *(const bf16x8*)(apr + ((kq * 128 + ks * 32 + kh * 8) ^ rsw));
            acc = __builtin_amdgcn_mfma_f32_16x16x32_bf16(a, bx[ks], acc, 0, 0, 0);
        }

        // ---- barrier: wait for row-group to finish step t-1 ----
        if (t > 0) {
            unsigned int v;
            do {
                asm volatile("global_load_dword %0, %1, off sc0 sc1\n\t"
                             "s_waitcnt vmcnt(0)"
                             : "=v"(v) : "v"(pollp) : "memory");
            } while (!__all(v >= (unsigned int)t));
        }

        // ---- prefetch x_{t+1} (plain cached loads, overlaps h staging) ----
        if (t + 1 < TT) {
            #pragma unroll
            for (int i = 0; i < 4; ++i)
                xpf[i] = *(const float4*)(xrow_ptr + (size_t)(t + 1) * 512 + i * 4);
        }

        // ---- stage h-half: 2 x 16B per thread from hb[cur] ----
        {
            const unsigned short* hsrc = hb + (size_t)cur * NN * HH
                                       + (size_t)(rowbase + srow) * HH + scol * 16;
            int4v h0v, h1v;
            asm volatile("global_load_dwordx4 %0, %1, off sc0 sc1" : "=v"(h0v) : "v"(hsrc));
            asm volatile("global_load_dwordx4 %0, %1, off sc0 sc1" : "=v"(h1v) : "v"(hsrc + 8));
            asm volatile("s_waitcnt vmcnt(0)" ::: "memory");
            int k0u = 512 + scol * 16;
            *(int4v*)(Ap + srow * 1024 + (k0u ^ rws))       = h0v;
            *(int4v*)(Ap + srow * 1024 + ((k0u + 8) ^ rws)) = h1v;
        }
        __syncthreads();   // s2: h-half visible

        // ---- h-GEMM: 4 MFMA ----
        #pragma unroll
        for (int ks = 0; ks < 4; ++ks) {
            bf16x8 a = *(const bf16x8*)(apr + ((512 + kq * 128 + ks * 32 + kh * 8) ^ rsw));
            acc = __builtin_amdgcn_mfma_f32_16x16x32_bf16(a, bh[ks], acc, 0, 0, 0);
        }
        #pragma unroll
        for (int rr = 0; rr < 4; ++rr)
            part[wv][kh * 4 + rr][l15] = acc[rr];
        __syncthreads();   // s3: all partials written

        // ---- reduce 4 K-quarters ----
        {
            int row = tid >> 5;
            int lc2 = tid & 31;
            int ct2 = lc2 >> 4;
            int cc  = lc2 & 15;
            As[row][lc2] = part[ct2][row][cc] + part[2 + ct2][row][cc]
                         + part[4 + ct2][row][cc] + part[6 + ct2][row][cc];
        }
        __syncthreads();   // s4: As ready

        // ---- gates: 128 cells (16 rows x 8 j) ----
        if (tid < 128) {
            float Ai = As[grow_l][q]      + bi;
            float Af = As[grow_l][8 + q]  + bf_;
            float Ao = As[grow_l][16 + q] + bo;
            float Ag = As[grow_l][24 + q] + bg;
            float ig = 1.f / (1.f + __expf(-Ai));
            float fg = 1.f / (1.f + __expf(-Af));
            float og = 1.f / (1.f + __expf(-Ao));
            float gg = tanhf(Ag);
            c_reg = fg * c_reg + ig * gg;
            float hn = og * tanhf(c_reg);
            outp[(size_t)t * HH] = hn;
            unsigned int hv = (unsigned int)f2bf(hn);
            unsigned short* hdst = hdst0 + (size_t)nxt * NN * HH;
            asm volatile("global_store_short %0, %1, off sc0 sc1" :: "v"(hdst), "v"(hv) : "memory");
        }

        // ---- publish flag = t+1 ----
        if (t + 1 < TT) {
            asm volatile("s_waitcnt vmcnt(0)" ::: "memory");
            __syncthreads();   // s5: all h stores drained block-wide
            if (tid == 0) {
                unsigned int target = (unsigned int)(t + 1);
                asm volatile("global_store_dword %0, %1, off sc0 sc1"
                             :: "v"(myflag), "v"(target) : "memory");
            }
        }
    }
}

extern "C" void kernel_launch(void* const* d_in, const int* in_sizes, int n_in,
                              void* d_out, int out_size, void* d_ws, size_t ws_size,
                              hipStream_t stream)
{
    const float* x  = (const float*)d_in[0];
    const float* h0 = (const float*)d_in[1];
    const float* Wx = (const float*)d_in[2];
    const float* Wh = (const float*)d_in[3];
    const float* b  = (const float*)d_in[4];
    float* out = (float*)d_out;

    char* ws = (char*)d_ws;
    unsigned short* Wt  = (unsigned short*)ws;                                      // 4 MB
    unsigned short* hb  = (unsigned short*)(ws + (size_t)4 * 1024 * 1024);          // 128 KB
    unsigned int*   flg = (unsigned int*)(ws + (size_t)4 * 1024 * 1024 + 131072);   // 16 KB

    prep_wt<<<dim3(32, 16), 256, 0, stream>>>(Wx, Wh, Wt);
    lstm_init<<<128, 256, 0, stream>>>(h0, hb, flg);
    lstm_persist<<<256, 512, 0, stream>>>(x, Wt, b, out, hb, flg);
}